// Round 5
// baseline (1329.633 us; speedup 1.0000x reference)
//
#include <hip/hip_runtime.h>
#include <hip/hip_bf16.h>

#define VOCAB 32000
#define HIDDEN 1024
#define BATCH 32
#define SEQ 128

typedef short bf8v __attribute__((ext_vector_type(8)));   // 8 x bf16 payload
typedef float f32x4 __attribute__((ext_vector_type(4)));
typedef unsigned long long u64;
typedef unsigned int u32;

static __device__ __forceinline__ short f2bf(float f) {
    return __builtin_bit_cast(short, __float2bfloat16(f));
}
static __device__ __forceinline__ float bf2f(short s) {
    unsigned u = ((unsigned)(unsigned short)s) << 16;
    return __builtin_bit_cast(float, u);
}

// -------- Phase 0: transpose f32 (K rows x N cols) -> bf16 (N rows x K cols) ----
__global__ __launch_bounds__(256) void transpose_f32_bf16(
    const float* __restrict__ in, short* __restrict__ out, int K, int N) {
    __shared__ short tile[64][65];
    int ntiles = N >> 6;
    int bn = blockIdx.x % ntiles;
    int bk = blockIdx.x / ntiles;
    int tid = threadIdx.x;
#pragma unroll
    for (int i = 0; i < 16; ++i) {
        int idx = i * 256 + tid;
        int lk = idx >> 6;
        int ln = idx & 63;
        float v = in[(size_t)(bk * 64 + lk) * N + (bn * 64 + ln)];
        tile[ln][lk] = f2bf(v);
    }
    __syncthreads();
#pragma unroll
    for (int i = 0; i < 16; ++i) {
        int idx = i * 256 + tid;
        int lnr = idx >> 6;
        int lkc = idx & 63;
        out[(size_t)(bn * 64 + lnr) * K + (bk * 64 + lkc)] = tile[lnr][lkc];
    }
}

__global__ __launch_bounds__(256) void f32_to_bf16_vec(
    const float* __restrict__ in, short* __restrict__ out, int n) {
    int i = blockIdx.x * 256 + threadIdx.x;
    if (i < n) out[i] = f2bf(in[i]);
}

// -------- Phase 1: persistent recurrence, data-as-flag exchange --------------
// 64 blocks x 256 thr. Block (bgi=bid>>4, cgj=bid&15) owns h[8*bgi..+8][64*cgj..+64].
// It needs only ITS 8 rows of h_prev (written by its 15 same-bgi siblings).
// Exchange: tagged u32 = (bf16<<16)|(t+1) in a depth-2 ping-pong buffer; readers
// poll tags directly (no barrier, no fences, 1 MALL trip per step). Depth-2 is
// safe: a block writes tag t+2 only after reading ALL of h_{t+1}, which implies
// every sibling finished reading tag t. Tags 1..128 never collide with 0x0/0xAA
// poison or the t-shifted leftovers of a previous replay (slot parity differs).
__global__ __launch_bounds__(256) void rnn_persistent(
    const short* __restrict__ WhhT,   // (1024 n, 1024 k) bf16
    const float* __restrict__ Wxh,    // (VOCAB, 1024) f32
    const float* __restrict__ bh,     // (1024) f32
    const int*   __restrict__ x,      // (BATCH, SEQ) int32
    const short* __restrict__ S0,     // (32,1024) bf16 initial state
    short* __restrict__ H,            // (SEQ, 32, 1024) bf16 (plain, for gemm)
    u32* __restrict__ Htag)           // (2, 32, 1024) u32 tagged ping-pong
{
    __shared__ short Wl[64 * 1024];   // 128 KB: 64 W-cols x 1024 k, XOR-swizzled
    __shared__ short hl[8 * 1024];    // 16 KB: 8 batch rows x 1024 k, XOR-swizzled
    const int tid = threadIdx.x;
    const int bgi = blockIdx.x >> 4;  // 0..3  batch-row group
    const int cgj = blockIdx.x & 15;  // 0..15 column group
    const int grow0 = bgi * 8;
    const int gcol0 = cgj * 64;

    // W slice -> LDS (granule g of local col c stored at phys g^(c&7))
    for (int i = tid; i < 64 * 128; i += 256) {
        int c = i >> 7, g = i & 127;
        bf8v wv = *(const bf8v*)(WhhT + ((size_t)(gcol0 + c) << 10) + (g << 3));
        *(bf8v*)(Wl + (c << 10) + ((g ^ (c & 7)) << 3)) = wv;
    }
    // initial h rows from S0 -> hl
    {
        const u64* s = (const u64*)(S0 + (grow0 << 10));
#pragma unroll
        for (int j = 0; j < 8; ++j) {
            int idx = tid + 256 * j;          // u64 index in 8x1024 bf16 region
            int r = idx >> 8, cq = idx & 255; // 256 u64 per row; u64 = 4 bf16
            u64 v = s[idx];
            *(u64*)((char*)hl + (r << 11) + (((cq >> 1) ^ (r & 7)) << 4) + ((cq & 1) << 3)) = v;
        }
    }

    const int lane = tid & 63, wv_ = tid >> 6;
    const int lrow = lane & 15, kg = lane >> 4;
    const int rx = lrow & 7;
    const int gcol = gcol0 + wv_ * 16 + lrow;   // h column this lane produces
    const float bias = bh[gcol];
    const short* aBase = hl + ((lrow & 7) << 10);        // rows 8-15 alias 0-7 (dup, unstored)
    const short* bBase = Wl + (((wv_ << 4) + lrow) << 10);
    const bool act = (kg < 2);                  // D rows kg*4+r valid only for kg<2

    int xc[4] = {0, 0, 0, 0};
    if (act)
#pragma unroll
        for (int r = 0; r < 4; ++r) xc[r] = x[(grow0 + kg * 4 + r) * SEQ];

    for (int t = 0; t < SEQ; ++t) {
        // embedding gathers: issued first, consumed in epilogue (latency hidden)
        float wx[4] = {0.f, 0.f, 0.f, 0.f};
        if (act)
#pragma unroll
            for (int r = 0; r < 4; ++r) wx[r] = Wxh[((size_t)xc[r] << 10) + gcol];

        if (t > 0) {
            // poll + read our 8 rows of h_{t-1} (tag == t) from ping-pong slot
            const u64 want64 = (u64)(u32)t * 0x0000000100000001ull;
            const u64* base = (const u64*)(Htag + (((t - 1) & 1) << 15)) + (grow0 << 9);
            u64 vv[16];
#pragma unroll
            for (int j = 0; j < 16; ++j)
                vv[j] = __hip_atomic_load(base + tid + 256 * j,
                                          __ATOMIC_RELAXED, __HIP_MEMORY_SCOPE_AGENT);
#pragma unroll
            for (int j = 0; j < 16; ++j)
                while ((vv[j] & 0x0000FFFF0000FFFFull) != want64)
                    vv[j] = __hip_atomic_load(base + tid + 256 * j,
                                              __ATOMIC_RELAXED, __HIP_MEMORY_SCOPE_AGENT);
#pragma unroll
            for (int j = 0; j < 16; ++j) {
                int idx = tid + 256 * j;           // u64 idx in 8x512 region
                int r = idx >> 9, c2 = idx & 511;  // u64 = 2 cols
                u32 pk = ((u32)(vv[j] >> 16) & 0xFFFFu) | ((u32)(vv[j] >> 32) & 0xFFFF0000u);
                *(u32*)((char*)hl + (r << 11) + (((c2 >> 2) ^ (r & 7)) << 4) + ((c2 & 3) << 2)) = pk;
            }
        }
        asm volatile("s_waitcnt lgkmcnt(0)" ::: "memory");
        __builtin_amdgcn_s_barrier();
        __builtin_amdgcn_sched_barrier(0);

        f32x4 acc = {0.f, 0.f, 0.f, 0.f};
#pragma unroll
        for (int it = 0; it < 32; ++it) {
            int off = ((4 * it + kg) ^ rx) << 3;
            bf8v a = *(const bf8v*)(aBase + off);
            bf8v b = *(const bf8v*)(bBase + off);
            acc = __builtin_amdgcn_mfma_f32_16x16x32_bf16(a, b, acc, 0, 0, 0);
        }

        int tn = (t + 1 < SEQ) ? t + 1 : SEQ - 1;
        int xn[4] = {0, 0, 0, 0};
        if (act)
#pragma unroll
            for (int r = 0; r < 4; ++r) xn[r] = x[(grow0 + kg * 4 + r) * SEQ + tn];

        if (act) {
            const u32 wtag = (u32)(t + 1);
            u32* tagbuf = Htag + ((t & 1) << 15);
            short* Ht = H + ((size_t)t << 15);
#pragma unroll
            for (int r = 0; r < 4; ++r) {
                int grow = grow0 + kg * 4 + r;     // D map: col=lane&15, row=(lane>>4)*4+r
                float v = tanhf(wx[r] + acc[r] + bias);
                short bv = f2bf(v);
                __hip_atomic_store(tagbuf + (grow << 10) + gcol,
                                   ((u32)(unsigned short)bv << 16) | wtag,
                                   __ATOMIC_RELAXED, __HIP_MEMORY_SCOPE_AGENT);
                Ht[(grow << 10) + gcol] = bv;      // plain copy for gemm (async)
            }
        }
#pragma unroll
        for (int r = 0; r < 4; ++r) xc[r] = xn[r];

        // protect hl before next step's reload; do NOT drain vmcnt (stores async)
        asm volatile("s_waitcnt lgkmcnt(0)" ::: "memory");
        __builtin_amdgcn_s_barrier();
        __builtin_amdgcn_sched_barrier(0);
    }
}

// -------- Phase 2: big output GEMM  C = H @ WhoT^T + b_o --------------------
// m97 structure: 128x128 tile, BK=64, global_load_lds(16B) with source-XOR
// swizzle (linear LDS dest, pre-swizzled global src), 2 barriers per K-step.
__global__ __launch_bounds__(256) void gemm_out(
    const short* __restrict__ A,
    const short* __restrict__ B,
    const float* __restrict__ bo,
    float* __restrict__ C)
{
    __shared__ short As[128 * 64];   // [row][k], 128B rows, XOR-swizzled granules
    __shared__ short Bs[128 * 64];

    // XCD-aware swizzle (grid 8000 % 8 == 0 -> bijective)
    int nwg = gridDim.x;
    int cpx = nwg >> 3;
    int bid = blockIdx.x;
    int swz = (bid & 7) * cpx + (bid >> 3);
    int bm = swz % 32;   // m fastest: consecutive blocks share the B panel
    int bn = swz / 32;

    int tid = threadIdx.x;
    int lane = tid & 63;
    int wid = tid >> 6;
    int wm = wid >> 1, wn = wid & 1;
    int lrow = lane & 15, kg = lane >> 4;
    int rx = lrow & 7;

    const size_t a0 = (size_t)bm * 128;
    const size_t b0 = (size_t)bn * 128;

    // staging: lane -> chunk row (lane>>3) + phys granule (lane&7);
    // src granule = phys ^ (row&7)  => LDS[row][g] == M[row][g ^ (row&7)]
    int srow = lane >> 3, sg = lane & 7;
    int sxor = (sg ^ srow) << 3;     // shorts

    f32x4 acc[4][4] = {};

    for (int kk = 0; kk < HIDDEN; kk += 64) {
        __syncthreads();   // previous iteration's ds_reads complete
#pragma unroll
        for (int c = 0; c < 4; ++c) {
            int crow = (wid * 4 + c) * 8;   // wave-uniform chunk base (8 rows x 64k)
            const short* srcA = A + (a0 + crow + srow) * HIDDEN + kk + sxor;
            __builtin_amdgcn_global_load_lds(
                (const __attribute__((address_space(1))) void*)srcA,
                (__attribute__((address_space(3))) void*)(As + crow * 64), 16, 0, 0);
            const short* srcB = B + (b0 + crow + srow) * HIDDEN + kk + sxor;
            __builtin_amdgcn_global_load_lds(
                (const __attribute__((address_space(1))) void*)srcB,
                (__attribute__((address_space(3))) void*)(Bs + crow * 64), 16, 0, 0);
        }
        __syncthreads();   // compiler drains vmcnt(0) before barrier

#pragma unroll
        for (int kh = 0; kh < 2; ++kh) {
            int off = (((kh << 2) + kg) ^ rx) << 3;
            bf8v af[4], bfr[4];
#pragma unroll
            for (int mi = 0; mi < 4; ++mi)
                af[mi] = *(const bf8v*)(As + (wm * 64 + mi * 16 + lrow) * 64 + off);
#pragma unroll
            for (int nj = 0; nj < 4; ++nj)
                bfr[nj] = *(const bf8v*)(Bs + (wn * 64 + nj * 16 + lrow) * 64 + off);
#pragma unroll
            for (int mi = 0; mi < 4; ++mi)
#pragma unroll
                for (int nj = 0; nj < 4; ++nj)
                    acc[mi][nj] = __builtin_amdgcn_mfma_f32_16x16x32_bf16(
                        af[mi], bfr[nj], acc[mi][nj], 0, 0, 0);
        }
    }

    // epilogue: D col = lane&15, row = (lane>>4)*4 + r
    size_t crow_base = a0 + wm * 64;
    int ccol_base = (int)b0 + wn * 64;
#pragma unroll
    for (int nj = 0; nj < 4; ++nj) {
        int col = ccol_base + nj * 16 + lrow;
        float bias = bo[col];
#pragma unroll
        for (int mi = 0; mi < 4; ++mi) {
#pragma unroll
            for (int r = 0; r < 4; ++r) {
                size_t row = crow_base + mi * 16 + kg * 4 + r;
                C[row * VOCAB + col] = acc[mi][nj][r] + bias;
            }
        }
    }
}

// -------- final_state: bf16 h_127 -> f32 ------------------------------------
__global__ __launch_bounds__(256) void write_final(
    const short* __restrict__ Hlast, float* __restrict__ out) {
    int i = blockIdx.x * 256 + threadIdx.x;
    if (i < BATCH * HIDDEN) out[i] = bf2f(Hlast[i]);
}

extern "C" void kernel_launch(void* const* d_in, const int* in_sizes, int n_in,
                              void* d_out, int out_size, void* d_ws, size_t ws_size,
                              hipStream_t stream) {
    const int*   x   = (const int*)  d_in[0];
    const float* st  = (const float*)d_in[1];
    const float* Wxh = (const float*)d_in[2];
    const float* Whh = (const float*)d_in[3];
    const float* bh  = (const float*)d_in[4];
    const float* Who = (const float*)d_in[5];
    const float* bo  = (const float*)d_in[6];
    float* out = (float*)d_out;

    char* ws = (char*)d_ws;
    short* WhhT = (short*)ws;                                           // 2 MB
    short* WhoT = (short*)(ws + 2097152ull);                            // 65.536 MB
    short* H    = (short*)(ws + 2097152ull + 65536000ull);              // 8.389 MB
    short* S0   = (short*)(ws + 2097152ull + 65536000ull + 8388608ull); // 64 KB
    u32*   Htag = (u32*)  (ws + 2097152ull + 65536000ull + 8388608ull + 65536ull); // 256 KB

    transpose_f32_bf16<<<(1024/64)*(1024/64), 256, 0, stream>>>(Whh, WhhT, 1024, 1024);
    transpose_f32_bf16<<<(VOCAB/64)*(1024/64), 256, 0, stream>>>(Who, WhoT, 1024, VOCAB);
    f32_to_bf16_vec<<<(BATCH*HIDDEN + 255)/256, 256, 0, stream>>>(st, S0, BATCH*HIDDEN);
    hipMemsetAsync(Htag, 0, 2ull * BATCH * HIDDEN * sizeof(u32), stream);

    rnn_persistent<<<64, 256, 0, stream>>>(WhhT, Wxh, bh, x, S0, H, Htag);

    gemm_out<<<(4096/128) * (VOCAB/128), 256, 0, stream>>>(H, WhoT, bo, out);
    write_final<<<(BATCH*HIDDEN + 255)/256, 256, 0, stream>>>(
        H + (size_t)(SEQ - 1) * BATCH * HIDDEN, out + (size_t)SEQ * BATCH * VOCAB);
}

// Round 6
// 949.282 us; speedup vs baseline: 1.4007x; 1.4007x over previous
//
#include <hip/hip_runtime.h>
#include <hip/hip_bf16.h>

#define VOCAB 32000
#define HIDDEN 1024
#define BATCH 32
#define SEQ 128

typedef short bf8v __attribute__((ext_vector_type(8)));   // 8 x bf16 payload
typedef float f32x4 __attribute__((ext_vector_type(4)));
typedef unsigned long long u64;
typedef unsigned int u32;

static __device__ __forceinline__ short f2bf(float f) {
    return __builtin_bit_cast(short, __float2bfloat16(f));
}
static __device__ __forceinline__ float bf2f(short s) {
    unsigned u = ((unsigned)(unsigned short)s) << 16;
    return __builtin_bit_cast(float, u);
}

// -------- Phase 0: transpose f32 (K rows x N cols) -> bf16 (N rows x K cols) ----
__global__ __launch_bounds__(256) void transpose_f32_bf16(
    const float* __restrict__ in, short* __restrict__ out, int K, int N) {
    __shared__ short tile[64][65];
    int ntiles = N >> 6;
    int bn = blockIdx.x % ntiles;
    int bk = blockIdx.x / ntiles;
    int tid = threadIdx.x;
#pragma unroll
    for (int i = 0; i < 16; ++i) {
        int idx = i * 256 + tid;
        int lk = idx >> 6;
        int ln = idx & 63;
        float v = in[(size_t)(bk * 64 + lk) * N + (bn * 64 + ln)];
        tile[ln][lk] = f2bf(v);
    }
    __syncthreads();
#pragma unroll
    for (int i = 0; i < 16; ++i) {
        int idx = i * 256 + tid;
        int lnr = idx >> 6;
        int lkc = idx & 63;
        out[(size_t)(bn * 64 + lnr) * K + (bk * 64 + lkc)] = tile[lnr][lkc];
    }
}

__global__ __launch_bounds__(256) void f32_to_bf16_vec(
    const float* __restrict__ in, short* __restrict__ out, int n) {
    int i = blockIdx.x * 256 + threadIdx.x;
    if (i < n) out[i] = f2bf(in[i]);
}

// -------- Phase 1: persistent recurrence, data-as-flag exchange --------------
// 64 blocks x 256 thr. Block (bgi=bid>>4, cgj=bid&15) owns h[8*bgi..+8][64*cgj..+64].
// Exchange: tagged u32 = (bf16<<16)|(t+1), depth-2 ping-pong, PARALLEL poll:
// issue all 16 u64 loads, check all, re-issue all on miss (rounds = max skew,
// not sum). Stale replay data is benign (replays are deterministic).
// Loop order per step: MFMA -> tanh/stores -> issue x/Wxh gathers for t+1
// (soaks one MALL trip) -> poll -> LDS stage -> barrier.
__global__ __launch_bounds__(256) void rnn_persistent(
    const short* __restrict__ WhhT,   // (1024 n, 1024 k) bf16
    const float* __restrict__ Wxh,    // (VOCAB, 1024) f32
    const float* __restrict__ bh,     // (1024) f32
    const int*   __restrict__ x,      // (BATCH, SEQ) int32
    const short* __restrict__ S0,     // (32,1024) bf16 initial state
    short* __restrict__ H,            // (SEQ, 32, 1024) bf16 (plain, for gemm)
    u32* __restrict__ Htag)           // (2, 32, 1024) u32 tagged ping-pong
{
    __shared__ short Wl[64 * 1024];   // 128 KB: 64 W-cols x 1024 k, XOR-swizzled
    __shared__ short hl[8 * 1024];    // 16 KB: 8 batch rows x 1024 k, XOR-swizzled
    const int tid = threadIdx.x;
    const int bgi = blockIdx.x >> 4;  // 0..3  batch-row group
    const int cgj = blockIdx.x & 15;  // 0..15 column group
    const int grow0 = bgi * 8;
    const int gcol0 = cgj * 64;

    // W slice -> LDS (granule g of local col c stored at phys g^(c&7))
    for (int i = tid; i < 64 * 128; i += 256) {
        int c = i >> 7, g = i & 127;
        bf8v wv = *(const bf8v*)(WhhT + ((size_t)(gcol0 + c) << 10) + (g << 3));
        *(bf8v*)(Wl + (c << 10) + ((g ^ (c & 7)) << 3)) = wv;
    }
    // initial h rows from S0 -> hl
    {
        const u64* s = (const u64*)(S0 + (grow0 << 10));
#pragma unroll
        for (int j = 0; j < 8; ++j) {
            int idx = tid + 256 * j;          // u64 index in 8x1024 bf16 region
            int r = idx >> 8, cq = idx & 255; // 256 u64 per row; u64 = 4 bf16
            u64 v = s[idx];
            *(u64*)((char*)hl + (r << 11) + (((cq >> 1) ^ (r & 7)) << 4) + ((cq & 1) << 3)) = v;
        }
    }

    const int lane = tid & 63, wv_ = tid >> 6;
    const int lrow = lane & 15, kg = lane >> 4;
    const int rx = lrow & 7;
    const int gcol = gcol0 + wv_ * 16 + lrow;   // h column this lane produces
    const float bias = bh[gcol];
    const short* aBase = hl + ((lrow & 7) << 10);   // rows 8-15 alias 0-7 (dup)
    const short* bBase = Wl + (((wv_ << 4) + lrow) << 10);
    const bool act = (kg < 2);                  // D rows kg*4+r valid only for kg<2

    // gathers for t=0
    float wx[4] = {0.f, 0.f, 0.f, 0.f};
    if (act)
#pragma unroll
        for (int r = 0; r < 4; ++r) {
            int id = x[(grow0 + kg * 4 + r) * SEQ];
            wx[r] = Wxh[((size_t)id << 10) + gcol];
        }
    __syncthreads();

    for (int t = 0; t < SEQ; ++t) {
        // ---- MFMA on h_{t-1} (in hl) ----
        f32x4 acc = {0.f, 0.f, 0.f, 0.f};
#pragma unroll
        for (int it = 0; it < 32; ++it) {
            int off = ((4 * it + kg) ^ rx) << 3;
            bf8v a = *(const bf8v*)(aBase + off);
            bf8v b = *(const bf8v*)(bBase + off);
            acc = __builtin_amdgcn_mfma_f32_16x16x32_bf16(a, b, acc, 0, 0, 0);
        }

        // ---- tanh + tagged store (slot t&1, tag t+1) + plain H store ----
        if (act) {
            const u32 wtag = (u32)(t + 1);
            u32* tagbuf = Htag + ((t & 1) << 15);
            short* Ht = H + ((size_t)t << 15);
#pragma unroll
            for (int r = 0; r < 4; ++r) {
                int grow = grow0 + kg * 4 + r;  // D map: col=lane&15, row=(lane>>4)*4+r
                float v = tanhf(wx[r] + acc[r] + bias);
                short bv = f2bf(v);
                __hip_atomic_store(tagbuf + (grow << 10) + gcol,
                                   ((u32)(unsigned short)bv << 16) | wtag,
                                   __ATOMIC_RELAXED, __HIP_MEMORY_SCOPE_AGENT);
                Ht[(grow << 10) + gcol] = bv;   // async; drained by poll waits
            }
        }

        if (t + 1 < SEQ) {
            // ---- issue x + Wxh gather chain for t+1 (hides under poll) ----
            if (act)
#pragma unroll
                for (int r = 0; r < 4; ++r) {
                    int id = x[(grow0 + kg * 4 + r) * SEQ + (t + 1)];
                    wx[r] = Wxh[((size_t)id << 10) + gcol];
                }

            // ---- parallel poll for h_t (tag t+1) ----
            const u64 want = (u64)(u32)(t + 1) * 0x0000000100000001ull;
            const u64* base = (const u64*)(Htag + ((t & 1) << 15)) + (grow0 << 9);
            u64 vv[16];
#pragma unroll
            for (int j = 0; j < 16; ++j)
                vv[j] = __hip_atomic_load(base + tid + 256 * j,
                                          __ATOMIC_RELAXED, __HIP_MEMORY_SCOPE_AGENT);
            for (;;) {
                bool ok = true;
#pragma unroll
                for (int j = 0; j < 16; ++j)
                    ok &= ((vv[j] & 0x0000FFFF0000FFFFull) == want);
                if (ok) break;
#pragma unroll
                for (int j = 0; j < 16; ++j)
                    vv[j] = __hip_atomic_load(base + tid + 256 * j,
                                              __ATOMIC_RELAXED, __HIP_MEMORY_SCOPE_AGENT);
            }
            // ---- strip tags, stage into hl (swizzled) ----
#pragma unroll
            for (int j = 0; j < 16; ++j) {
                int idx = tid + 256 * j;           // u64 idx in 8x512 region
                int r = idx >> 9, c2 = idx & 511;  // u64 = 2 tagged cols
                u32 pk = ((u32)(vv[j] >> 16) & 0xFFFFu) | ((u32)(vv[j] >> 32) & 0xFFFF0000u);
                *(u32*)((char*)hl + (r << 11) + (((c2 >> 2) ^ (r & 7)) << 4) + ((c2 & 3) << 2)) = pk;
            }
        }

        asm volatile("s_waitcnt lgkmcnt(0)" ::: "memory");
        __builtin_amdgcn_s_barrier();
        __builtin_amdgcn_sched_barrier(0);
    }
}

// -------- Phase 2: big output GEMM  C = H @ WhoT^T + b_o --------------------
// m97 structure: 128x128 tile, BK=64, global_load_lds(16B) with source-XOR
// swizzle (linear LDS dest, pre-swizzled global src), 2 barriers per K-step.
__global__ __launch_bounds__(256) void gemm_out(
    const short* __restrict__ A,
    const short* __restrict__ B,
    const float* __restrict__ bo,
    float* __restrict__ C)
{
    __shared__ short As[128 * 64];   // [row][k], 128B rows, XOR-swizzled granules
    __shared__ short Bs[128 * 64];

    // XCD-aware swizzle (grid 8000 % 8 == 0 -> bijective)
    int nwg = gridDim.x;
    int cpx = nwg >> 3;
    int bid = blockIdx.x;
    int swz = (bid & 7) * cpx + (bid >> 3);
    int bm = swz % 32;   // m fastest: consecutive blocks share the B panel
    int bn = swz / 32;

    int tid = threadIdx.x;
    int lane = tid & 63;
    int wid = tid >> 6;
    int wm = wid >> 1, wn = wid & 1;
    int lrow = lane & 15, kg = lane >> 4;
    int rx = lrow & 7;

    const size_t a0 = (size_t)bm * 128;
    const size_t b0 = (size_t)bn * 128;

    // staging: lane -> chunk row (lane>>3) + phys granule (lane&7);
    // src granule = phys ^ (row&7)  => LDS[row][g] == M[row][g ^ (row&7)]
    int srow = lane >> 3, sg = lane & 7;
    int sxor = (sg ^ srow) << 3;     // shorts

    f32x4 acc[4][4] = {};

    for (int kk = 0; kk < HIDDEN; kk += 64) {
        __syncthreads();   // previous iteration's ds_reads complete
#pragma unroll
        for (int c = 0; c < 4; ++c) {
            int crow = (wid * 4 + c) * 8;   // wave-uniform chunk base (8 rows x 64k)
            const short* srcA = A + (a0 + crow + srow) * HIDDEN + kk + sxor;
            __builtin_amdgcn_global_load_lds(
                (const __attribute__((address_space(1))) void*)srcA,
                (__attribute__((address_space(3))) void*)(As + crow * 64), 16, 0, 0);
            const short* srcB = B + (b0 + crow + srow) * HIDDEN + kk + sxor;
            __builtin_amdgcn_global_load_lds(
                (const __attribute__((address_space(1))) void*)srcB,
                (__attribute__((address_space(3))) void*)(Bs + crow * 64), 16, 0, 0);
        }
        __syncthreads();   // compiler drains vmcnt(0) before barrier

#pragma unroll
        for (int kh = 0; kh < 2; ++kh) {
            int off = (((kh << 2) + kg) ^ rx) << 3;
            bf8v af[4], bfr[4];
#pragma unroll
            for (int mi = 0; mi < 4; ++mi)
                af[mi] = *(const bf8v*)(As + (wm * 64 + mi * 16 + lrow) * 64 + off);
#pragma unroll
            for (int nj = 0; nj < 4; ++nj)
                bfr[nj] = *(const bf8v*)(Bs + (wn * 64 + nj * 16 + lrow) * 64 + off);
#pragma unroll
            for (int mi = 0; mi < 4; ++mi)
#pragma unroll
                for (int nj = 0; nj < 4; ++nj)
                    acc[mi][nj] = __builtin_amdgcn_mfma_f32_16x16x32_bf16(
                        af[mi], bfr[nj], acc[mi][nj], 0, 0, 0);
        }
    }

    // epilogue: D col = lane&15, row = (lane>>4)*4 + r
    size_t crow_base = a0 + wm * 64;
    int ccol_base = (int)b0 + wn * 64;
#pragma unroll
    for (int nj = 0; nj < 4; ++nj) {
        int col = ccol_base + nj * 16 + lrow;
        float bias = bo[col];
#pragma unroll
        for (int mi = 0; mi < 4; ++mi) {
#pragma unroll
            for (int r = 0; r < 4; ++r) {
                size_t row = crow_base + mi * 16 + kg * 4 + r;
                C[row * VOCAB + col] = acc[mi][nj][r] + bias;
            }
        }
    }
}

// -------- final_state: bf16 h_127 -> f32 ------------------------------------
__global__ __launch_bounds__(256) void write_final(
    const short* __restrict__ Hlast, float* __restrict__ out) {
    int i = blockIdx.x * 256 + threadIdx.x;
    if (i < BATCH * HIDDEN) out[i] = bf2f(Hlast[i]);
}

extern "C" void kernel_launch(void* const* d_in, const int* in_sizes, int n_in,
                              void* d_out, int out_size, void* d_ws, size_t ws_size,
                              hipStream_t stream) {
    const int*   x   = (const int*)  d_in[0];
    const float* st  = (const float*)d_in[1];
    const float* Wxh = (const float*)d_in[2];
    const float* Whh = (const float*)d_in[3];
    const float* bh  = (const float*)d_in[4];
    const float* Who = (const float*)d_in[5];
    const float* bo  = (const float*)d_in[6];
    float* out = (float*)d_out;

    char* ws = (char*)d_ws;
    short* WhhT = (short*)ws;                                           // 2 MB
    short* WhoT = (short*)(ws + 2097152ull);                            // 65.536 MB
    short* H    = (short*)(ws + 2097152ull + 65536000ull);              // 8.389 MB
    short* S0   = (short*)(ws + 2097152ull + 65536000ull + 8388608ull); // 64 KB
    u32*   Htag = (u32*)  (ws + 2097152ull + 65536000ull + 8388608ull + 65536ull); // 256 KB

    transpose_f32_bf16<<<(1024/64)*(1024/64), 256, 0, stream>>>(Whh, WhhT, 1024, 1024);
    transpose_f32_bf16<<<(VOCAB/64)*(1024/64), 256, 0, stream>>>(Who, WhoT, 1024, VOCAB);
    f32_to_bf16_vec<<<(BATCH*HIDDEN + 255)/256, 256, 0, stream>>>(st, S0, BATCH*HIDDEN);
    hipMemsetAsync(Htag, 0, 2ull * BATCH * HIDDEN * sizeof(u32), stream);

    rnn_persistent<<<64, 256, 0, stream>>>(WhhT, Wxh, bh, x, S0, H, Htag);

    gemm_out<<<(4096/128) * (VOCAB/128), 256, 0, stream>>>(H, WhoT, bo, out);
    write_final<<<(BATCH*HIDDEN + 255)/256, 256, 0, stream>>>(
        H + (size_t)(SEQ - 1) * BATCH * HIDDEN, out + (size_t)SEQ * BATCH * VOCAB);
}

// Round 7
// 797.132 us; speedup vs baseline: 1.6680x; 1.1909x over previous
//
#include <hip/hip_runtime.h>
#include <hip/hip_bf16.h>

#define VOCAB 32000
#define HIDDEN 1024
#define BATCH 32
#define SEQ 128

typedef short bf8v __attribute__((ext_vector_type(8)));   // 8 x bf16 payload
typedef float f32x4 __attribute__((ext_vector_type(4)));
typedef unsigned long long u64;
typedef unsigned int u32;

static __device__ __forceinline__ short f2bf(float f) {
    return __builtin_bit_cast(short, __float2bfloat16(f));
}
static __device__ __forceinline__ float bf2f(short s) {
    unsigned u = ((unsigned)(unsigned short)s) << 16;
    return __builtin_bit_cast(float, u);
}

// -------- Phase 0: transpose f32 (K rows x N cols) -> bf16 (N rows x K cols) ----
// nt loads: Who is 128 MB read-once -> don't let it evict L3 content.
__global__ __launch_bounds__(256) void transpose_f32_bf16(
    const float* __restrict__ in, short* __restrict__ out, int K, int N) {
    __shared__ short tile[64][65];
    int ntiles = N >> 6;
    int bn = blockIdx.x % ntiles;
    int bk = blockIdx.x / ntiles;
    int tid = threadIdx.x;
#pragma unroll
    for (int i = 0; i < 16; ++i) {
        int idx = i * 256 + tid;
        int lk = idx >> 6;
        int ln = idx & 63;
        float v = __builtin_nontemporal_load(
            &in[(size_t)(bk * 64 + lk) * N + (bn * 64 + ln)]);
        tile[ln][lk] = f2bf(v);
    }
    __syncthreads();
#pragma unroll
    for (int i = 0; i < 16; ++i) {
        int idx = i * 256 + tid;
        int lnr = idx >> 6;
        int lkc = idx & 63;
        out[(size_t)(bn * 64 + lnr) * K + (bk * 64 + lkc)] = tile[lnr][lkc];
    }
}

__global__ __launch_bounds__(256) void f32_to_bf16_vec(
    const float* __restrict__ in, short* __restrict__ out, int n) {
    int i = blockIdx.x * 256 + threadIdx.x;
    if (i < n) out[i] = f2bf(in[i]);
}

// -------- Phase 1: persistent recurrence, data-as-flag exchange --------------
// (unchanged from round 6 — parallel poll, depth-2 tagged ping-pong)
__global__ __launch_bounds__(256) void rnn_persistent(
    const short* __restrict__ WhhT,   // (1024 n, 1024 k) bf16
    const float* __restrict__ Wxh,    // (VOCAB, 1024) f32
    const float* __restrict__ bh,     // (1024) f32
    const int*   __restrict__ x,      // (BATCH, SEQ) int32
    const short* __restrict__ S0,     // (32,1024) bf16 initial state
    short* __restrict__ H,            // (SEQ, 32, 1024) bf16 (plain, for gemm)
    u32* __restrict__ Htag)           // (2, 32, 1024) u32 tagged ping-pong
{
    __shared__ short Wl[64 * 1024];   // 128 KB: 64 W-cols x 1024 k, XOR-swizzled
    __shared__ short hl[8 * 1024];    // 16 KB: 8 batch rows x 1024 k, XOR-swizzled
    const int tid = threadIdx.x;
    const int bgi = blockIdx.x >> 4;  // 0..3  batch-row group
    const int cgj = blockIdx.x & 15;  // 0..15 column group
    const int grow0 = bgi * 8;
    const int gcol0 = cgj * 64;

    // W slice -> LDS (granule g of local col c stored at phys g^(c&7))
    for (int i = tid; i < 64 * 128; i += 256) {
        int c = i >> 7, g = i & 127;
        bf8v wv = *(const bf8v*)(WhhT + ((size_t)(gcol0 + c) << 10) + (g << 3));
        *(bf8v*)(Wl + (c << 10) + ((g ^ (c & 7)) << 3)) = wv;
    }
    // initial h rows from S0 -> hl
    {
        const u64* s = (const u64*)(S0 + (grow0 << 10));
#pragma unroll
        for (int j = 0; j < 8; ++j) {
            int idx = tid + 256 * j;          // u64 index in 8x1024 bf16 region
            int r = idx >> 8, cq = idx & 255; // 256 u64 per row; u64 = 4 bf16
            u64 v = s[idx];
            *(u64*)((char*)hl + (r << 11) + (((cq >> 1) ^ (r & 7)) << 4) + ((cq & 1) << 3)) = v;
        }
    }

    const int lane = tid & 63, wv_ = tid >> 6;
    const int lrow = lane & 15, kg = lane >> 4;
    const int rx = lrow & 7;
    const int gcol = gcol0 + wv_ * 16 + lrow;   // h column this lane produces
    const float bias = bh[gcol];
    const short* aBase = hl + ((lrow & 7) << 10);   // rows 8-15 alias 0-7 (dup)
    const short* bBase = Wl + (((wv_ << 4) + lrow) << 10);
    const bool act = (kg < 2);                  // D rows kg*4+r valid only for kg<2

    // gathers for t=0
    float wx[4] = {0.f, 0.f, 0.f, 0.f};
    if (act)
#pragma unroll
        for (int r = 0; r < 4; ++r) {
            int id = x[(grow0 + kg * 4 + r) * SEQ];
            wx[r] = Wxh[((size_t)id << 10) + gcol];
        }
    __syncthreads();

    for (int t = 0; t < SEQ; ++t) {
        // ---- MFMA on h_{t-1} (in hl) ----
        f32x4 acc = {0.f, 0.f, 0.f, 0.f};
#pragma unroll
        for (int it = 0; it < 32; ++it) {
            int off = ((4 * it + kg) ^ rx) << 3;
            bf8v a = *(const bf8v*)(aBase + off);
            bf8v b = *(const bf8v*)(bBase + off);
            acc = __builtin_amdgcn_mfma_f32_16x16x32_bf16(a, b, acc, 0, 0, 0);
        }

        // ---- tanh + tagged store (slot t&1, tag t+1) + plain H store ----
        if (act) {
            const u32 wtag = (u32)(t + 1);
            u32* tagbuf = Htag + ((t & 1) << 15);
            short* Ht = H + ((size_t)t << 15);
#pragma unroll
            for (int r = 0; r < 4; ++r) {
                int grow = grow0 + kg * 4 + r;  // D map: col=lane&15, row=(lane>>4)*4+r
                float v = tanhf(wx[r] + acc[r] + bias);
                short bv = f2bf(v);
                __hip_atomic_store(tagbuf + (grow << 10) + gcol,
                                   ((u32)(unsigned short)bv << 16) | wtag,
                                   __ATOMIC_RELAXED, __HIP_MEMORY_SCOPE_AGENT);
                Ht[(grow << 10) + gcol] = bv;   // async; drained by poll waits
            }
        }

        if (t + 1 < SEQ) {
            // ---- issue x + Wxh gather chain for t+1 (hides under poll) ----
            if (act)
#pragma unroll
                for (int r = 0; r < 4; ++r) {
                    int id = x[(grow0 + kg * 4 + r) * SEQ + (t + 1)];
                    wx[r] = Wxh[((size_t)id << 10) + gcol];
                }

            // ---- parallel poll for h_t (tag t+1) ----
            const u64 want = (u64)(u32)(t + 1) * 0x0000000100000001ull;
            const u64* base = (const u64*)(Htag + ((t & 1) << 15)) + (grow0 << 9);
            u64 vv[16];
#pragma unroll
            for (int j = 0; j < 16; ++j)
                vv[j] = __hip_atomic_load(base + tid + 256 * j,
                                          __ATOMIC_RELAXED, __HIP_MEMORY_SCOPE_AGENT);
            for (;;) {
                bool ok = true;
#pragma unroll
                for (int j = 0; j < 16; ++j)
                    ok &= ((vv[j] & 0x0000FFFF0000FFFFull) == want);
                if (ok) break;
#pragma unroll
                for (int j = 0; j < 16; ++j)
                    vv[j] = __hip_atomic_load(base + tid + 256 * j,
                                              __ATOMIC_RELAXED, __HIP_MEMORY_SCOPE_AGENT);
            }
            // ---- strip tags, stage into hl (swizzled) ----
#pragma unroll
            for (int j = 0; j < 16; ++j) {
                int idx = tid + 256 * j;           // u64 idx in 8x512 region
                int r = idx >> 9, c2 = idx & 511;  // u64 = 2 tagged cols
                u32 pk = ((u32)(vv[j] >> 16) & 0xFFFFu) | ((u32)(vv[j] >> 32) & 0xFFFF0000u);
                *(u32*)((char*)hl + (r << 11) + (((c2 >> 2) ^ (r & 7)) << 4) + ((c2 & 3) << 2)) = pk;
            }
        }

        asm volatile("s_waitcnt lgkmcnt(0)" ::: "memory");
        __builtin_amdgcn_s_barrier();
        __builtin_amdgcn_sched_barrier(0);
    }
}

// -------- Phase 2: big output GEMM  C = H @ WhoT^T + b_o --------------------
// m97 structure: 128x128 tile, BK=64, global_load_lds(16B) with source-XOR
// swizzle, 2 barriers per K-step. C stores are NON-TEMPORAL: the 524 MB
// output stream must not allocate in L3, so the A/B panels (72 MB total)
// stay L3-resident across the whole grid sweep.
__global__ __launch_bounds__(256) void gemm_out(
    const short* __restrict__ A,
    const short* __restrict__ B,
    const float* __restrict__ bo,
    float* __restrict__ C)
{
    __shared__ short As[128 * 64];   // [row][k], 128B rows, XOR-swizzled granules
    __shared__ short Bs[128 * 64];

    // XCD-aware swizzle (grid 8000 % 8 == 0 -> bijective)
    int nwg = gridDim.x;
    int cpx = nwg >> 3;
    int bid = blockIdx.x;
    int swz = (bid & 7) * cpx + (bid >> 3);
    int bm = swz % 32;   // m fastest: consecutive blocks share the B panel
    int bn = swz / 32;

    int tid = threadIdx.x;
    int lane = tid & 63;
    int wid = tid >> 6;
    int wm = wid >> 1, wn = wid & 1;
    int lrow = lane & 15, kg = lane >> 4;
    int rx = lrow & 7;

    const size_t a0 = (size_t)bm * 128;
    const size_t b0 = (size_t)bn * 128;

    // staging: lane -> chunk row (lane>>3) + phys granule (lane&7);
    // src granule = phys ^ (row&7)  => LDS[row][g] == M[row][g ^ (row&7)]
    int srow = lane >> 3, sg = lane & 7;
    int sxor = (sg ^ srow) << 3;     // shorts

    f32x4 acc[4][4] = {};

    for (int kk = 0; kk < HIDDEN; kk += 64) {
        __syncthreads();   // previous iteration's ds_reads complete
#pragma unroll
        for (int c = 0; c < 4; ++c) {
            int crow = (wid * 4 + c) * 8;   // wave-uniform chunk base (8 rows x 64k)
            const short* srcA = A + (a0 + crow + srow) * HIDDEN + kk + sxor;
            __builtin_amdgcn_global_load_lds(
                (const __attribute__((address_space(1))) void*)srcA,
                (__attribute__((address_space(3))) void*)(As + crow * 64), 16, 0, 0);
            const short* srcB = B + (b0 + crow + srow) * HIDDEN + kk + sxor;
            __builtin_amdgcn_global_load_lds(
                (const __attribute__((address_space(1))) void*)srcB,
                (__attribute__((address_space(3))) void*)(Bs + crow * 64), 16, 0, 0);
        }
        __syncthreads();   // compiler drains vmcnt(0) before barrier

#pragma unroll
        for (int kh = 0; kh < 2; ++kh) {
            int off = (((kh << 2) + kg) ^ rx) << 3;
            bf8v af[4], bfr[4];
#pragma unroll
            for (int mi = 0; mi < 4; ++mi)
                af[mi] = *(const bf8v*)(As + (wm * 64 + mi * 16 + lrow) * 64 + off);
#pragma unroll
            for (int nj = 0; nj < 4; ++nj)
                bfr[nj] = *(const bf8v*)(Bs + (wn * 64 + nj * 16 + lrow) * 64 + off);
#pragma unroll
            for (int mi = 0; mi < 4; ++mi)
#pragma unroll
                for (int nj = 0; nj < 4; ++nj)
                    acc[mi][nj] = __builtin_amdgcn_mfma_f32_16x16x32_bf16(
                        af[mi], bfr[nj], acc[mi][nj], 0, 0, 0);
        }
    }

    // epilogue: D col = lane&15, row = (lane>>4)*4 + r ; NT stores
    size_t crow_base = a0 + wm * 64;
    int ccol_base = (int)b0 + wn * 64;
#pragma unroll
    for (int nj = 0; nj < 4; ++nj) {
        int col = ccol_base + nj * 16 + lrow;
        float bias = bo[col];
#pragma unroll
        for (int mi = 0; mi < 4; ++mi) {
#pragma unroll
            for (int r = 0; r < 4; ++r) {
                size_t row = crow_base + mi * 16 + kg * 4 + r;
                __builtin_nontemporal_store(acc[mi][nj][r] + bias,
                                            &C[row * VOCAB + col]);
            }
        }
    }
}

// -------- final_state: bf16 h_127 -> f32 ------------------------------------
__global__ __launch_bounds__(256) void write_final(
    const short* __restrict__ Hlast, float* __restrict__ out) {
    int i = blockIdx.x * 256 + threadIdx.x;
    if (i < BATCH * HIDDEN) out[i] = bf2f(Hlast[i]);
}

extern "C" void kernel_launch(void* const* d_in, const int* in_sizes, int n_in,
                              void* d_out, int out_size, void* d_ws, size_t ws_size,
                              hipStream_t stream) {
    const int*   x   = (const int*)  d_in[0];
    const float* st  = (const float*)d_in[1];
    const float* Wxh = (const float*)d_in[2];
    const float* Whh = (const float*)d_in[3];
    const float* bh  = (const float*)d_in[4];
    const float* Who = (const float*)d_in[5];
    const float* bo  = (const float*)d_in[6];
    float* out = (float*)d_out;

    char* ws = (char*)d_ws;
    short* WhhT = (short*)ws;                                           // 2 MB
    short* WhoT = (short*)(ws + 2097152ull);                            // 65.536 MB
    short* H    = (short*)(ws + 2097152ull + 65536000ull);              // 8.389 MB
    short* S0   = (short*)(ws + 2097152ull + 65536000ull + 8388608ull); // 64 KB
    u32*   Htag = (u32*)  (ws + 2097152ull + 65536000ull + 8388608ull + 65536ull); // 256 KB

    transpose_f32_bf16<<<(1024/64)*(1024/64), 256, 0, stream>>>(Whh, WhhT, 1024, 1024);
    transpose_f32_bf16<<<(VOCAB/64)*(1024/64), 256, 0, stream>>>(Who, WhoT, 1024, VOCAB);
    f32_to_bf16_vec<<<(BATCH*HIDDEN + 255)/256, 256, 0, stream>>>(st, S0, BATCH*HIDDEN);
    hipMemsetAsync(Htag, 0, 2ull * BATCH * HIDDEN * sizeof(u32), stream);

    rnn_persistent<<<64, 256, 0, stream>>>(WhhT, Wxh, bh, x, S0, H, Htag);

    gemm_out<<<(4096/128) * (VOCAB/128), 256, 0, stream>>>(H, WhoT, bo, out);
    write_final<<<(BATCH*HIDDEN + 255)/256, 256, 0, stream>>>(
        H + (size_t)(SEQ - 1) * BATCH * HIDDEN, out + (size_t)SEQ * BATCH * VOCAB);
}

// Round 8
// 761.150 us; speedup vs baseline: 1.7469x; 1.0473x over previous
//
#include <hip/hip_runtime.h>
#include <hip/hip_bf16.h>

#define VOCAB 32000
#define HIDDEN 1024
#define BATCH 32
#define SEQ 128

typedef short bf8v __attribute__((ext_vector_type(8)));   // 8 x bf16 payload
typedef float f32x4 __attribute__((ext_vector_type(4)));
typedef unsigned long long u64;
typedef unsigned int u32;

static __device__ __forceinline__ short f2bf(float f) {
    return __builtin_bit_cast(short, __float2bfloat16(f));
}
static __device__ __forceinline__ float bf2f(short s) {
    unsigned u = ((unsigned)(unsigned short)s) << 16;
    return __builtin_bit_cast(float, u);
}

// -------- Phase 0: transpose f32 (K rows x N cols) -> bf16 (N rows x K cols) ----
__global__ __launch_bounds__(256) void transpose_f32_bf16(
    const float* __restrict__ in, short* __restrict__ out, int K, int N) {
    __shared__ short tile[64][65];
    int ntiles = N >> 6;
    int bn = blockIdx.x % ntiles;
    int bk = blockIdx.x / ntiles;
    int tid = threadIdx.x;
#pragma unroll
    for (int i = 0; i < 16; ++i) {
        int idx = i * 256 + tid;
        int lk = idx >> 6;
        int ln = idx & 63;
        float v = __builtin_nontemporal_load(
            &in[(size_t)(bk * 64 + lk) * N + (bn * 64 + ln)]);
        tile[ln][lk] = f2bf(v);
    }
    __syncthreads();
#pragma unroll
    for (int i = 0; i < 16; ++i) {
        int idx = i * 256 + tid;
        int lnr = idx >> 6;
        int lkc = idx & 63;
        out[(size_t)(bn * 64 + lnr) * K + (bk * 64 + lkc)] = tile[lnr][lkc];
    }
}

__global__ __launch_bounds__(256) void f32_to_bf16_vec(
    const float* __restrict__ in, short* __restrict__ out, int n) {
    int i = blockIdx.x * 256 + threadIdx.x;
    if (i < n) out[i] = f2bf(in[i]);
}

// -------- Phase 1: persistent recurrence (unchanged, proven) -----------------
__global__ __launch_bounds__(256) void rnn_persistent(
    const short* __restrict__ WhhT,   // (1024 n, 1024 k) bf16
    const float* __restrict__ Wxh,    // (VOCAB, 1024) f32
    const float* __restrict__ bh,     // (1024) f32
    const int*   __restrict__ x,      // (BATCH, SEQ) int32
    const short* __restrict__ S0,     // (32,1024) bf16 initial state
    short* __restrict__ H,            // (SEQ, 32, 1024) bf16 (plain, for gemm)
    u32* __restrict__ Htag)           // (2, 32, 1024) u32 tagged ping-pong
{
    __shared__ short Wl[64 * 1024];   // 128 KB: 64 W-cols x 1024 k, XOR-swizzled
    __shared__ short hl[8 * 1024];    // 16 KB: 8 batch rows x 1024 k, XOR-swizzled
    const int tid = threadIdx.x;
    const int bgi = blockIdx.x >> 4;  // 0..3  batch-row group
    const int cgj = blockIdx.x & 15;  // 0..15 column group
    const int grow0 = bgi * 8;
    const int gcol0 = cgj * 64;

    for (int i = tid; i < 64 * 128; i += 256) {
        int c = i >> 7, g = i & 127;
        bf8v wv = *(const bf8v*)(WhhT + ((size_t)(gcol0 + c) << 10) + (g << 3));
        *(bf8v*)(Wl + (c << 10) + ((g ^ (c & 7)) << 3)) = wv;
    }
    {
        const u64* s = (const u64*)(S0 + (grow0 << 10));
#pragma unroll
        for (int j = 0; j < 8; ++j) {
            int idx = tid + 256 * j;
            int r = idx >> 8, cq = idx & 255;
            u64 v = s[idx];
            *(u64*)((char*)hl + (r << 11) + (((cq >> 1) ^ (r & 7)) << 4) + ((cq & 1) << 3)) = v;
        }
    }

    const int lane = tid & 63, wv_ = tid >> 6;
    const int lrow = lane & 15, kg = lane >> 4;
    const int rx = lrow & 7;
    const int gcol = gcol0 + wv_ * 16 + lrow;
    const float bias = bh[gcol];
    const short* aBase = hl + ((lrow & 7) << 10);
    const short* bBase = Wl + (((wv_ << 4) + lrow) << 10);
    const bool act = (kg < 2);

    float wx[4] = {0.f, 0.f, 0.f, 0.f};
    if (act)
#pragma unroll
        for (int r = 0; r < 4; ++r) {
            int id = x[(grow0 + kg * 4 + r) * SEQ];
            wx[r] = Wxh[((size_t)id << 10) + gcol];
        }
    __syncthreads();

    for (int t = 0; t < SEQ; ++t) {
        f32x4 acc = {0.f, 0.f, 0.f, 0.f};
#pragma unroll
        for (int it = 0; it < 32; ++it) {
            int off = ((4 * it + kg) ^ rx) << 3;
            bf8v a = *(const bf8v*)(aBase + off);
            bf8v b = *(const bf8v*)(bBase + off);
            acc = __builtin_amdgcn_mfma_f32_16x16x32_bf16(a, b, acc, 0, 0, 0);
        }

        if (act) {
            const u32 wtag = (u32)(t + 1);
            u32* tagbuf = Htag + ((t & 1) << 15);
            short* Ht = H + ((size_t)t << 15);
#pragma unroll
            for (int r = 0; r < 4; ++r) {
                int grow = grow0 + kg * 4 + r;
                float v = tanhf(wx[r] + acc[r] + bias);
                short bv = f2bf(v);
                __hip_atomic_store(tagbuf + (grow << 10) + gcol,
                                   ((u32)(unsigned short)bv << 16) | wtag,
                                   __ATOMIC_RELAXED, __HIP_MEMORY_SCOPE_AGENT);
                Ht[(grow << 10) + gcol] = bv;
            }
        }

        if (t + 1 < SEQ) {
            if (act)
#pragma unroll
                for (int r = 0; r < 4; ++r) {
                    int id = x[(grow0 + kg * 4 + r) * SEQ + (t + 1)];
                    wx[r] = Wxh[((size_t)id << 10) + gcol];
                }

            const u64 want = (u64)(u32)(t + 1) * 0x0000000100000001ull;
            const u64* base = (const u64*)(Htag + ((t & 1) << 15)) + (grow0 << 9);
            u64 vv[16];
#pragma unroll
            for (int j = 0; j < 16; ++j)
                vv[j] = __hip_atomic_load(base + tid + 256 * j,
                                          __ATOMIC_RELAXED, __HIP_MEMORY_SCOPE_AGENT);
            for (;;) {
                bool ok = true;
#pragma unroll
                for (int j = 0; j < 16; ++j)
                    ok &= ((vv[j] & 0x0000FFFF0000FFFFull) == want);
                if (ok) break;
#pragma unroll
                for (int j = 0; j < 16; ++j)
                    vv[j] = __hip_atomic_load(base + tid + 256 * j,
                                              __ATOMIC_RELAXED, __HIP_MEMORY_SCOPE_AGENT);
            }
#pragma unroll
            for (int j = 0; j < 16; ++j) {
                int idx = tid + 256 * j;
                int r = idx >> 9, c2 = idx & 511;
                u32 pk = ((u32)(vv[j] >> 16) & 0xFFFFu) | ((u32)(vv[j] >> 32) & 0xFFFF0000u);
                *(u32*)((char*)hl + (r << 11) + (((c2 >> 2) ^ (r & 7)) << 4) + ((c2 & 3) << 2)) = pk;
            }
        }

        asm volatile("s_waitcnt lgkmcnt(0)" ::: "memory");
        __builtin_amdgcn_s_barrier();
        __builtin_amdgcn_sched_barrier(0);
    }
}

// -------- Phase 2: counted-vmcnt ring-pipelined GEMM ------------------------
// C = H(4096x1024) @ WhoT(32000x1024)^T + b_o, C (4096,32000) f32.
// BM=256 x BN=128, BK=64, 512 thr / 8 waves (4m x 2n), 64x64 per wave.
// LDS: 3-slot ring, 48 KB/slot (A 32K + B 16K). Per K-tile t:
//   vmcnt(6) gate (tile t's stage landed; t+1's stays in flight)
//   s_barrier  (all waves' reads of slot (t+2)%3 finished at tile t-1)
//   issue stage(t+2)   <- safe: after barrier; data lands before t+2's gate
//   ds_read frags; lgkmcnt(0); setprio(1); 32 MFMA; setprio(0)
// Loads never drain to 0 in the main loop (T3/T4). Epilogue reuses the dead
// ring as per-wave scratch to emit full-128B-line NT dwordx4 C stores.
#define SLOT_BYTES 49152
__global__ __launch_bounds__(512, 2) void gemm_out(
    const short* __restrict__ A,
    const short* __restrict__ B,
    const float* __restrict__ bo,
    float* __restrict__ C)
{
    __shared__ char ring[3 * SLOT_BYTES];   // 144 KB

    // XCD-aware swizzle (grid 4000 % 8 == 0 -> bijective)
    int nwg = gridDim.x;
    int cpx = nwg >> 3;
    int bid = blockIdx.x;
    int swz = (bid & 7) * cpx + (bid >> 3);
    int bm = swz & 15;    // m fastest: consecutive blocks share the B panel
    int bn = swz >> 4;

    const int tid = threadIdx.x;
    const int lane = tid & 63;
    const int wid = tid >> 6;          // 0..7
    const int wm = wid >> 1;           // 0..3 (64-row M slice)
    const int wn = wid & 1;            // 0..1 (64-col N slice)
    const int lrow = lane & 15, kg = lane >> 4;
    const int rx = lrow & 7;

    const size_t a0 = (size_t)bm * 256;
    const size_t b0 = (size_t)bn * 128;

    // staging: thread -> row band; src granule pre-XOR'd so LDS is linear
    const int srow8 = (lane >> 3) & 7;       // row within 8-row band
    const int sxor = ((lane & 7) ^ srow8) << 3;   // element offset in 64-k row

    f32x4 acc[4][4] = {};

#define STAGE(T)                                                                \
    {                                                                           \
        char* slot = ring + ((T) % 3) * SLOT_BYTES;                             \
        const int kk = (T) * 64;                                                \
        _Pragma("unroll")                                                       \
        for (int i = 0; i < 4; ++i) {                                           \
            const short* srcA = A + (a0 + i * 64 + wid * 8 + srow8) * HIDDEN    \
                                  + kk + sxor;                                  \
            __builtin_amdgcn_global_load_lds(                                   \
                (const __attribute__((address_space(1))) void*)srcA,            \
                (__attribute__((address_space(3))) void*)                       \
                    (slot + (i * 64 + wid * 8) * 128), 16, 0, 0);               \
        }                                                                       \
        _Pragma("unroll")                                                       \
        for (int j = 0; j < 2; ++j) {                                           \
            const short* srcB = B + (b0 + j * 64 + wid * 8 + srow8) * HIDDEN    \
                                  + kk + sxor;                                  \
            __builtin_amdgcn_global_load_lds(                                   \
                (const __attribute__((address_space(1))) void*)srcB,            \
                (__attribute__((address_space(3))) void*)                       \
                    (slot + 32768 + (j * 64 + wid * 8) * 128), 16, 0, 0);       \
        }                                                                       \
    }

    STAGE(0);
    STAGE(1);

#pragma unroll 1
    for (int t = 0; t < 16; ++t) {
        if (t < 15) {
            asm volatile("s_waitcnt vmcnt(6)" ::: "memory");
        } else {
            asm volatile("s_waitcnt vmcnt(0)" ::: "memory");
        }
        __builtin_amdgcn_sched_barrier(0);
        __builtin_amdgcn_s_barrier();
        __builtin_amdgcn_sched_barrier(0);
        if (t + 2 < 16) STAGE(t + 2);

        char* slot = ring + (t % 3) * SLOT_BYTES;
        bf8v af[4][2], bf_[4][2];
#pragma unroll
        for (int mi = 0; mi < 4; ++mi)
#pragma unroll
            for (int ks = 0; ks < 2; ++ks)
                af[mi][ks] = *(const bf8v*)(slot + (wm * 64 + mi * 16 + lrow) * 128
                                            + ((((ks << 2) + kg) ^ rx) << 4));
#pragma unroll
        for (int nj = 0; nj < 4; ++nj)
#pragma unroll
            for (int ks = 0; ks < 2; ++ks)
                bf_[nj][ks] = *(const bf8v*)(slot + 32768
                                             + (wn * 64 + nj * 16 + lrow) * 128
                                             + ((((ks << 2) + kg) ^ rx) << 4));
        asm volatile("s_waitcnt lgkmcnt(0)" ::: "memory");
        __builtin_amdgcn_sched_barrier(0);
        __builtin_amdgcn_s_setprio(1);
#pragma unroll
        for (int ks = 0; ks < 2; ++ks)
#pragma unroll
            for (int mi = 0; mi < 4; ++mi)
#pragma unroll
                for (int nj = 0; nj < 4; ++nj)
                    acc[mi][nj] = __builtin_amdgcn_mfma_f32_16x16x32_bf16(
                        af[mi][ks], bf_[nj][ks], acc[mi][nj], 0, 0, 0);
        __builtin_amdgcn_s_setprio(0);
        __builtin_amdgcn_sched_barrier(0);
    }
#undef STAGE

    // ---- epilogue: repack via (dead) ring LDS -> full-line NT stores ----
    __builtin_amdgcn_s_barrier();     // all waves done reading the ring
    char* wbase = ring + wid * 16384; // per-wave 64x64 f32 scratch
#pragma unroll
    for (int nj = 0; nj < 4; ++nj) {
        float bias = bo[b0 + wn * 64 + nj * 16 + lrow];
#pragma unroll
        for (int mi = 0; mi < 4; ++mi)
#pragma unroll
            for (int r = 0; r < 4; ++r)
                *(float*)(wbase + (mi * 16 + kg * 4 + r) * 256
                          + (nj * 16 + lrow) * 4) = acc[mi][nj][r] + bias;
    }
    asm volatile("s_waitcnt lgkmcnt(0)" ::: "memory");   // wave-local RAW
    __builtin_amdgcn_sched_barrier(0);
#pragma unroll
    for (int p = 0; p < 16; ++p) {
        f32x4 v = *(const f32x4*)(wbase + (p * 4 + (lane >> 4)) * 256
                                  + (lane & 15) * 16);
        size_t row_g = a0 + wm * 64 + p * 4 + (lane >> 4);
        int col_g = (int)b0 + wn * 64 + (lane & 15) * 4;
        __builtin_nontemporal_store(v, (f32x4*)&C[row_g * VOCAB + col_g]);
    }
}

// -------- final_state: bf16 h_127 -> f32 ------------------------------------
__global__ __launch_bounds__(256) void write_final(
    const short* __restrict__ Hlast, float* __restrict__ out) {
    int i = blockIdx.x * 256 + threadIdx.x;
    if (i < BATCH * HIDDEN) out[i] = bf2f(Hlast[i]);
}

extern "C" void kernel_launch(void* const* d_in, const int* in_sizes, int n_in,
                              void* d_out, int out_size, void* d_ws, size_t ws_size,
                              hipStream_t stream) {
    const int*   x   = (const int*)  d_in[0];
    const float* st  = (const float*)d_in[1];
    const float* Wxh = (const float*)d_in[2];
    const float* Whh = (const float*)d_in[3];
    const float* bh  = (const float*)d_in[4];
    const float* Who = (const float*)d_in[5];
    const float* bo  = (const float*)d_in[6];
    float* out = (float*)d_out;

    char* ws = (char*)d_ws;
    short* WhhT = (short*)ws;                                           // 2 MB
    short* WhoT = (short*)(ws + 2097152ull);                            // 65.536 MB
    short* H    = (short*)(ws + 2097152ull + 65536000ull);              // 8.389 MB
    short* S0   = (short*)(ws + 2097152ull + 65536000ull + 8388608ull); // 64 KB
    u32*   Htag = (u32*)  (ws + 2097152ull + 65536000ull + 8388608ull + 65536ull); // 256 KB

    transpose_f32_bf16<<<(1024/64)*(1024/64), 256, 0, stream>>>(Whh, WhhT, 1024, 1024);
    transpose_f32_bf16<<<(VOCAB/64)*(1024/64), 256, 0, stream>>>(Who, WhoT, 1024, VOCAB);
    f32_to_bf16_vec<<<(BATCH*HIDDEN + 255)/256, 256, 0, stream>>>(st, S0, BATCH*HIDDEN);
    hipMemsetAsync(Htag, 0, 2ull * BATCH * HIDDEN * sizeof(u32), stream);

    rnn_persistent<<<64, 256, 0, stream>>>(WhhT, Wxh, bh, x, S0, H, Htag);

    gemm_out<<<(4096/256) * (VOCAB/128), 512, 0, stream>>>(H, WhoT, bo, out);
    write_final<<<(BATCH*HIDDEN + 255)/256, 256, 0, stream>>>(
        H + (size_t)(SEQ - 1) * BATCH * HIDDEN, out + (size_t)SEQ * BATCH * VOCAB);
}

// Round 9
// 689.972 us; speedup vs baseline: 1.9271x; 1.1032x over previous
//
#include <hip/hip_runtime.h>
#include <hip/hip_bf16.h>

#define VOCAB 32000
#define HIDDEN 1024
#define BATCH 32
#define SEQ 128

typedef short bf8v __attribute__((ext_vector_type(8)));   // 8 x bf16 payload
typedef float f32x4 __attribute__((ext_vector_type(4)));
typedef unsigned long long u64;
typedef unsigned int u32;

static __device__ __forceinline__ short f2bf(float f) {
    return __builtin_bit_cast(short, __float2bfloat16(f));
}
static __device__ __forceinline__ float bf2f(short s) {
    unsigned u = ((unsigned)(unsigned short)s) << 16;
    return __builtin_bit_cast(float, u);
}
// tanh via exp: exact at both saturation ends; |err| ~1e-7 << bf16 rounding
static __device__ __forceinline__ float fast_tanh(float v) {
    float e = __expf(2.0f * v);
    return 1.0f - 2.0f / (e + 1.0f);
}

// -------- Phase 0: transpose f32 (K rows x N cols) -> bf16 (N rows x K cols) ----
__global__ __launch_bounds__(256) void transpose_f32_bf16(
    const float* __restrict__ in, short* __restrict__ out, int K, int N) {
    __shared__ short tile[64][65];
    int ntiles = N >> 6;
    int bn = blockIdx.x % ntiles;
    int bk = blockIdx.x / ntiles;
    int tid = threadIdx.x;
#pragma unroll
    for (int i = 0; i < 16; ++i) {
        int idx = i * 256 + tid;
        int lk = idx >> 6;
        int ln = idx & 63;
        float v = __builtin_nontemporal_load(
            &in[(size_t)(bk * 64 + lk) * N + (bn * 64 + ln)]);
        tile[ln][lk] = f2bf(v);
    }
    __syncthreads();
#pragma unroll
    for (int i = 0; i < 16; ++i) {
        int idx = i * 256 + tid;
        int lnr = idx >> 6;
        int lkc = idx & 63;
        out[(size_t)(bn * 64 + lnr) * K + (bk * 64 + lkc)] = tile[lnr][lkc];
    }
}

__global__ __launch_bounds__(256) void f32_to_bf16_vec(
    const float* __restrict__ in, short* __restrict__ out, int n) {
    int i = blockIdx.x * 256 + threadIdx.x;
    if (i < n) out[i] = f2bf(in[i]);
}

// -------- Phase 1: persistent recurrence, W in registers --------------------
// 64 blocks x 256 thr, block (bgi,cgj) owns h[8*bgi..+8][64*cgj..+64].
// W_hh B-fragments live in VGPRs (wreg[32], 128 VGPRs/lane) -- W never
// changes, so B-side ds_reads were pure per-step waste. hl (8 rows of h,
// XOR-swizzled) is the only LDS. Exchange: depth-2 tagged ping-pong with
// parallel poll (round 6, proven).
__global__ __launch_bounds__(256, 1) void rnn_persistent(
    const short* __restrict__ WhhT,   // (1024 n, 1024 k) bf16
    const float* __restrict__ Wxh,    // (VOCAB, 1024) f32
    const float* __restrict__ bh,     // (1024) f32
    const int*   __restrict__ x,      // (BATCH, SEQ) int32
    const short* __restrict__ S0,     // (32,1024) bf16 initial state
    short* __restrict__ H,            // (SEQ, 32, 1024) bf16 (plain, for gemm)
    u32* __restrict__ Htag)           // (2, 32, 1024) u32 tagged ping-pong
{
    __shared__ short hl[8 * 1024];    // 16 KB: 8 batch rows x 1024 k, XOR-swizzled
    const int tid = threadIdx.x;
    const int bgi = blockIdx.x >> 4;  // 0..3  batch-row group
    const int cgj = blockIdx.x & 15;  // 0..15 column group
    const int grow0 = bgi * 8;
    const int gcol0 = cgj * 64;

    const int lane = tid & 63, wv_ = tid >> 6;
    const int lrow = lane & 15, kg = lane >> 4;
    const int rx = lrow & 7;
    const int gcol = gcol0 + wv_ * 16 + lrow;   // h column this lane produces
    const float bias = bh[gcol];
    const short* aBase = hl + ((lrow & 7) << 10);   // rows 8-15 alias 0-7 (dup)
    const bool act = (kg < 2);

    // W_hh B-fragments -> registers (one-time; B[k][gcol] for k-chunk it)
    bf8v wreg[32];
#pragma unroll
    for (int it = 0; it < 32; ++it)
        wreg[it] = *(const bf8v*)(WhhT + ((size_t)gcol << 10) + it * 32 + kg * 8);

    // initial h rows from S0 -> hl
    {
        const u64* s = (const u64*)(S0 + (grow0 << 10));
#pragma unroll
        for (int j = 0; j < 8; ++j) {
            int idx = tid + 256 * j;
            int r = idx >> 8, cq = idx & 255;
            u64 v = s[idx];
            *(u64*)((char*)hl + (r << 11) + (((cq >> 1) ^ (r & 7)) << 4) + ((cq & 1) << 3)) = v;
        }
    }

    float wx[4] = {0.f, 0.f, 0.f, 0.f};
    if (act)
#pragma unroll
        for (int r = 0; r < 4; ++r) {
            int id = x[(grow0 + kg * 4 + r) * SEQ];
            wx[r] = Wxh[((size_t)id << 10) + gcol];
        }
    __syncthreads();

    for (int t = 0; t < SEQ; ++t) {
        // ---- MFMA on h_{t-1} (A from LDS, B from regs) ----
        f32x4 acc = {0.f, 0.f, 0.f, 0.f};
#pragma unroll
        for (int it = 0; it < 32; ++it) {
            int off = ((4 * it + kg) ^ rx) << 3;
            bf8v a = *(const bf8v*)(aBase + off);
            acc = __builtin_amdgcn_mfma_f32_16x16x32_bf16(a, wreg[it], acc, 0, 0, 0);
        }

        // ---- tanh + tagged store (slot t&1, tag t+1) + plain H store ----
        if (act) {
            const u32 wtag = (u32)(t + 1);
            u32* tagbuf = Htag + ((t & 1) << 15);
            short* Ht = H + ((size_t)t << 15);
#pragma unroll
            for (int r = 0; r < 4; ++r) {
                int grow = grow0 + kg * 4 + r;  // D map: col=lane&15, row=(lane>>4)*4+r
                float v = fast_tanh(wx[r] + acc[r] + bias);
                short bv = f2bf(v);
                __hip_atomic_store(tagbuf + (grow << 10) + gcol,
                                   ((u32)(unsigned short)bv << 16) | wtag,
                                   __ATOMIC_RELAXED, __HIP_MEMORY_SCOPE_AGENT);
                Ht[(grow << 10) + gcol] = bv;   // async; drained later
            }
        }

        if (t + 1 < SEQ) {
            // ---- x + Wxh gather chain for t+1 (hides under poll) ----
            if (act)
#pragma unroll
                for (int r = 0; r < 4; ++r) {
                    int id = x[(grow0 + kg * 4 + r) * SEQ + (t + 1)];
                    wx[r] = Wxh[((size_t)id << 10) + gcol];
                }

            // ---- parallel poll for h_t (tag t+1) ----
            const u64 want = (u64)(u32)(t + 1) * 0x0000000100000001ull;
            const u64* base = (const u64*)(Htag + ((t & 1) << 15)) + (grow0 << 9);
            u64 vv[16];
#pragma unroll
            for (int j = 0; j < 16; ++j)
                vv[j] = __hip_atomic_load(base + tid + 256 * j,
                                          __ATOMIC_RELAXED, __HIP_MEMORY_SCOPE_AGENT);
            for (;;) {
                bool ok = true;
#pragma unroll
                for (int j = 0; j < 16; ++j)
                    ok &= ((vv[j] & 0x0000FFFF0000FFFFull) == want);
                if (ok) break;
#pragma unroll
                for (int j = 0; j < 16; ++j)
                    vv[j] = __hip_atomic_load(base + tid + 256 * j,
                                              __ATOMIC_RELAXED, __HIP_MEMORY_SCOPE_AGENT);
            }

            // all waves past their MFMA reads of hl before we overwrite it
            __builtin_amdgcn_s_barrier();

            // ---- strip tags, stage into hl (swizzled) ----
#pragma unroll
            for (int j = 0; j < 16; ++j) {
                int idx = tid + 256 * j;
                int r = idx >> 9, c2 = idx & 511;
                u32 pk = ((u32)(vv[j] >> 16) & 0xFFFFu) | ((u32)(vv[j] >> 32) & 0xFFFF0000u);
                *(u32*)((char*)hl + (r << 11) + (((c2 >> 2) ^ (r & 7)) << 4) + ((c2 & 3) << 2)) = pk;
            }
        }

        asm volatile("s_waitcnt lgkmcnt(0)" ::: "memory");
        __builtin_amdgcn_s_barrier();
        __builtin_amdgcn_sched_barrier(0);
    }
}

// -------- Phase 2: counted-vmcnt ring-pipelined GEMM (unchanged, proven) ----
#define SLOT_BYTES 49152
__global__ __launch_bounds__(512, 2) void gemm_out(
    const short* __restrict__ A,
    const short* __restrict__ B,
    const float* __restrict__ bo,
    float* __restrict__ C)
{
    __shared__ char ring[3 * SLOT_BYTES];   // 144 KB

    int nwg = gridDim.x;
    int cpx = nwg >> 3;
    int bid = blockIdx.x;
    int swz = (bid & 7) * cpx + (bid >> 3);
    int bm = swz & 15;    // m fastest: consecutive blocks share the B panel
    int bn = swz >> 4;

    const int tid = threadIdx.x;
    const int lane = tid & 63;
    const int wid = tid >> 6;          // 0..7
    const int wm = wid >> 1;           // 0..3 (64-row M slice)
    const int wn = wid & 1;            // 0..1 (64-col N slice)
    const int lrow = lane & 15, kg = lane >> 4;
    const int rx = lrow & 7;

    const size_t a0 = (size_t)bm * 256;
    const size_t b0 = (size_t)bn * 128;

    const int srow8 = (lane >> 3) & 7;
    const int sxor = ((lane & 7) ^ srow8) << 3;

    f32x4 acc[4][4] = {};

#define STAGE(T)                                                                \
    {                                                                           \
        char* slot = ring + ((T) % 3) * SLOT_BYTES;                             \
        const int kk = (T) * 64;                                                \
        _Pragma("unroll")                                                       \
        for (int i = 0; i < 4; ++i) {                                           \
            const short* srcA = A + (a0 + i * 64 + wid * 8 + srow8) * HIDDEN    \
                                  + kk + sxor;                                  \
            __builtin_amdgcn_global_load_lds(                                   \
                (const __attribute__((address_space(1))) void*)srcA,            \
                (__attribute__((address_space(3))) void*)                       \
                    (slot + (i * 64 + wid * 8) * 128), 16, 0, 0);               \
        }                                                                       \
        _Pragma("unroll")                                                       \
        for (int j = 0; j < 2; ++j) {                                           \
            const short* srcB = B + (b0 + j * 64 + wid * 8 + srow8) * HIDDEN    \
                                  + kk + sxor;                                  \
            __builtin_amdgcn_global_load_lds(                                   \
                (const __attribute__((address_space(1))) void*)srcB,            \
                (__attribute__((address_space(3))) void*)                       \
                    (slot + 32768 + (j * 64 + wid * 8) * 128), 16, 0, 0);       \
        }                                                                       \
    }

    STAGE(0);
    STAGE(1);

#pragma unroll 1
    for (int t = 0; t < 16; ++t) {
        if (t < 15) {
            asm volatile("s_waitcnt vmcnt(6)" ::: "memory");
        } else {
            asm volatile("s_waitcnt vmcnt(0)" ::: "memory");
        }
        __builtin_amdgcn_sched_barrier(0);
        __builtin_amdgcn_s_barrier();
        __builtin_amdgcn_sched_barrier(0);
        if (t + 2 < 16) STAGE(t + 2);

        char* slot = ring + (t % 3) * SLOT_BYTES;
        bf8v af[4][2], bf_[4][2];
#pragma unroll
        for (int mi = 0; mi < 4; ++mi)
#pragma unroll
            for (int ks = 0; ks < 2; ++ks)
                af[mi][ks] = *(const bf8v*)(slot + (wm * 64 + mi * 16 + lrow) * 128
                                            + ((((ks << 2) + kg) ^ rx) << 4));
#pragma unroll
        for (int nj = 0; nj < 4; ++nj)
#pragma unroll
            for (int ks = 0; ks < 2; ++ks)
                bf_[nj][ks] = *(const bf8v*)(slot + 32768
                                             + (wn * 64 + nj * 16 + lrow) * 128
                                             + ((((ks << 2) + kg) ^ rx) << 4));
        asm volatile("s_waitcnt lgkmcnt(0)" ::: "memory");
        __builtin_amdgcn_sched_barrier(0);
        __builtin_amdgcn_s_setprio(1);
#pragma unroll
        for (int ks = 0; ks < 2; ++ks)
#pragma unroll
            for (int mi = 0; mi < 4; ++mi)
#pragma unroll
                for (int nj = 0; nj < 4; ++nj)
                    acc[mi][nj] = __builtin_amdgcn_mfma_f32_16x16x32_bf16(
                        af[mi][ks], bf_[nj][ks], acc[mi][nj], 0, 0, 0);
        __builtin_amdgcn_s_setprio(0);
        __builtin_amdgcn_sched_barrier(0);
    }
#undef STAGE

    // ---- epilogue: repack via (dead) ring LDS -> full-line NT stores ----
    __builtin_amdgcn_s_barrier();
    char* wbase = ring + wid * 16384;
#pragma unroll
    for (int nj = 0; nj < 4; ++nj) {
        float bias = bo[b0 + wn * 64 + nj * 16 + lrow];
#pragma unroll
        for (int mi = 0; mi < 4; ++mi)
#pragma unroll
            for (int r = 0; r < 4; ++r)
                *(float*)(wbase + (mi * 16 + kg * 4 + r) * 256
                          + (nj * 16 + lrow) * 4) = acc[mi][nj][r] + bias;
    }
    asm volatile("s_waitcnt lgkmcnt(0)" ::: "memory");
    __builtin_amdgcn_sched_barrier(0);
#pragma unroll
    for (int p = 0; p < 16; ++p) {
        f32x4 v = *(const f32x4*)(wbase + (p * 4 + (lane >> 4)) * 256
                                  + (lane & 15) * 16);
        size_t row_g = a0 + wm * 64 + p * 4 + (lane >> 4);
        int col_g = (int)b0 + wn * 64 + (lane & 15) * 4;
        __builtin_nontemporal_store(v, (f32x4*)&C[row_g * VOCAB + col_g]);
    }
}

// -------- final_state: bf16 h_127 -> f32 ------------------------------------
__global__ __launch_bounds__(256) void write_final(
    const short* __restrict__ Hlast, float* __restrict__ out) {
    int i = blockIdx.x * 256 + threadIdx.x;
    if (i < BATCH * HIDDEN) out[i] = bf2f(Hlast[i]);
}

extern "C" void kernel_launch(void* const* d_in, const int* in_sizes, int n_in,
                              void* d_out, int out_size, void* d_ws, size_t ws_size,
                              hipStream_t stream) {
    const int*   x   = (const int*)  d_in[0];
    const float* st  = (const float*)d_in[1];
    const float* Wxh = (const float*)d_in[2];
    const float* Whh = (const float*)d_in[3];
    const float* bh  = (const float*)d_in[4];
    const float* Who = (const float*)d_in[5];
    const float* bo  = (const float*)d_in[6];
    float* out = (float*)d_out;

    char* ws = (char*)d_ws;
    short* WhhT = (short*)ws;                                           // 2 MB
    short* WhoT = (short*)(ws + 2097152ull);                            // 65.536 MB
    short* H    = (short*)(ws + 2097152ull + 65536000ull);              // 8.389 MB
    short* S0   = (short*)(ws + 2097152ull + 65536000ull + 8388608ull); // 64 KB
    u32*   Htag = (u32*)  (ws + 2097152ull + 65536000ull + 8388608ull + 65536ull); // 256 KB

    transpose_f32_bf16<<<(1024/64)*(1024/64), 256, 0, stream>>>(Whh, WhhT, 1024, 1024);
    transpose_f32_bf16<<<(VOCAB/64)*(1024/64), 256, 0, stream>>>(Who, WhoT, 1024, VOCAB);
    f32_to_bf16_vec<<<(BATCH*HIDDEN + 255)/256, 256, 0, stream>>>(st, S0, BATCH*HIDDEN);
    hipMemsetAsync(Htag, 0, 2ull * BATCH * HIDDEN * sizeof(u32), stream);

    rnn_persistent<<<64, 256, 0, stream>>>(WhhT, Wxh, bh, x, S0, H, Htag);

    gemm_out<<<(4096/256) * (VOCAB/128), 512, 0, stream>>>(H, WhoT, bo, out);
    write_final<<<(BATCH*HIDDEN + 255)/256, 256, 0, stream>>>(
        H + (size_t)(SEQ - 1) * BATCH * HIDDEN, out + (size_t)SEQ * BATCH * VOCAB);
}

// Round 10
// 618.512 us; speedup vs baseline: 2.1497x; 1.1155x over previous
//
#include <hip/hip_runtime.h>
#include <hip/hip_bf16.h>

#define VOCAB 32000
#define HIDDEN 1024
#define BATCH 32
#define SEQ 128

typedef short bf8v __attribute__((ext_vector_type(8)));   // 8 x bf16 payload
typedef float f32x4 __attribute__((ext_vector_type(4)));
typedef unsigned long long u64;
typedef unsigned int u32;

static __device__ __forceinline__ short f2bf(float f) {
    return __builtin_bit_cast(short, __float2bfloat16(f));
}
static __device__ __forceinline__ float bf2f(short s) {
    unsigned u = ((unsigned)(unsigned short)s) << 16;
    return __builtin_bit_cast(float, u);
}
// tanh via exp: exact at both saturation ends; |err| ~1e-7 << bf16 rounding
static __device__ __forceinline__ float fast_tanh(float v) {
    float e = __expf(2.0f * v);
    return 1.0f - 2.0f / (e + 1.0f);
}

// -------- Phase 0: transpose f32 (K rows x N cols) -> bf16 (N rows x K cols) ----
__global__ __launch_bounds__(256) void transpose_f32_bf16(
    const float* __restrict__ in, short* __restrict__ out, int K, int N) {
    __shared__ short tile[64][65];
    int ntiles = N >> 6;
    int bn = blockIdx.x % ntiles;
    int bk = blockIdx.x / ntiles;
    int tid = threadIdx.x;
#pragma unroll
    for (int i = 0; i < 16; ++i) {
        int idx = i * 256 + tid;
        int lk = idx >> 6;
        int ln = idx & 63;
        float v = __builtin_nontemporal_load(
            &in[(size_t)(bk * 64 + lk) * N + (bn * 64 + ln)]);
        tile[ln][lk] = f2bf(v);
    }
    __syncthreads();
#pragma unroll
    for (int i = 0; i < 16; ++i) {
        int idx = i * 256 + tid;
        int lnr = idx >> 6;
        int lkc = idx & 63;
        out[(size_t)(bn * 64 + lnr) * K + (bk * 64 + lkc)] = tile[lnr][lkc];
    }
}

__global__ __launch_bounds__(256) void f32_to_bf16_vec(
    const float* __restrict__ in, short* __restrict__ out, int n) {
    int i = blockIdx.x * 256 + threadIdx.x;
    if (i < n) out[i] = f2bf(in[i]);
}

// -------- Phase 1: persistent recurrence, W in registers (unchanged) --------
__global__ __launch_bounds__(256, 1) void rnn_persistent(
    const short* __restrict__ WhhT,   // (1024 n, 1024 k) bf16
    const float* __restrict__ Wxh,    // (VOCAB, 1024) f32
    const float* __restrict__ bh,     // (1024) f32
    const int*   __restrict__ x,      // (BATCH, SEQ) int32
    const short* __restrict__ S0,     // (32,1024) bf16 initial state
    short* __restrict__ H,            // (SEQ, 32, 1024) bf16 (plain, for gemm)
    u32* __restrict__ Htag)           // (2, 32, 1024) u32 tagged ping-pong
{
    __shared__ short hl[8 * 1024];    // 16 KB: 8 batch rows x 1024 k, XOR-swizzled
    const int tid = threadIdx.x;
    const int bgi = blockIdx.x >> 4;  // 0..3  batch-row group
    const int cgj = blockIdx.x & 15;  // 0..15 column group
    const int grow0 = bgi * 8;
    const int gcol0 = cgj * 64;

    const int lane = tid & 63, wv_ = tid >> 6;
    const int lrow = lane & 15, kg = lane >> 4;
    const int rx = lrow & 7;
    const int gcol = gcol0 + wv_ * 16 + lrow;   // h column this lane produces
    const float bias = bh[gcol];
    const short* aBase = hl + ((lrow & 7) << 10);   // rows 8-15 alias 0-7 (dup)
    const bool act = (kg < 2);

    // W_hh B-fragments -> registers (one-time)
    bf8v wreg[32];
#pragma unroll
    for (int it = 0; it < 32; ++it)
        wreg[it] = *(const bf8v*)(WhhT + ((size_t)gcol << 10) + it * 32 + kg * 8);

    // initial h rows from S0 -> hl
    {
        const u64* s = (const u64*)(S0 + (grow0 << 10));
#pragma unroll
        for (int j = 0; j < 8; ++j) {
            int idx = tid + 256 * j;
            int r = idx >> 8, cq = idx & 255;
            u64 v = s[idx];
            *(u64*)((char*)hl + (r << 11) + (((cq >> 1) ^ (r & 7)) << 4) + ((cq & 1) << 3)) = v;
        }
    }

    float wx[4] = {0.f, 0.f, 0.f, 0.f};
    if (act)
#pragma unroll
        for (int r = 0; r < 4; ++r) {
            int id = x[(grow0 + kg * 4 + r) * SEQ];
            wx[r] = Wxh[((size_t)id << 10) + gcol];
        }
    __syncthreads();

    for (int t = 0; t < SEQ; ++t) {
        f32x4 acc = {0.f, 0.f, 0.f, 0.f};
#pragma unroll
        for (int it = 0; it < 32; ++it) {
            int off = ((4 * it + kg) ^ rx) << 3;
            bf8v a = *(const bf8v*)(aBase + off);
            acc = __builtin_amdgcn_mfma_f32_16x16x32_bf16(a, wreg[it], acc, 0, 0, 0);
        }

        if (act) {
            const u32 wtag = (u32)(t + 1);
            u32* tagbuf = Htag + ((t & 1) << 15);
            short* Ht = H + ((size_t)t << 15);
#pragma unroll
            for (int r = 0; r < 4; ++r) {
                int grow = grow0 + kg * 4 + r;
                float v = fast_tanh(wx[r] + acc[r] + bias);
                short bv = f2bf(v);
                __hip_atomic_store(tagbuf + (grow << 10) + gcol,
                                   ((u32)(unsigned short)bv << 16) | wtag,
                                   __ATOMIC_RELAXED, __HIP_MEMORY_SCOPE_AGENT);
                Ht[(grow << 10) + gcol] = bv;
            }
        }

        if (t + 1 < SEQ) {
            if (act)
#pragma unroll
                for (int r = 0; r < 4; ++r) {
                    int id = x[(grow0 + kg * 4 + r) * SEQ + (t + 1)];
                    wx[r] = Wxh[((size_t)id << 10) + gcol];
                }

            const u64 want = (u64)(u32)(t + 1) * 0x0000000100000001ull;
            const u64* base = (const u64*)(Htag + ((t & 1) << 15)) + (grow0 << 9);
            u64 vv[16];
#pragma unroll
            for (int j = 0; j < 16; ++j)
                vv[j] = __hip_atomic_load(base + tid + 256 * j,
                                          __ATOMIC_RELAXED, __HIP_MEMORY_SCOPE_AGENT);
            for (;;) {
                bool ok = true;
#pragma unroll
                for (int j = 0; j < 16; ++j)
                    ok &= ((vv[j] & 0x0000FFFF0000FFFFull) == want);
                if (ok) break;
#pragma unroll
                for (int j = 0; j < 16; ++j)
                    vv[j] = __hip_atomic_load(base + tid + 256 * j,
                                              __ATOMIC_RELAXED, __HIP_MEMORY_SCOPE_AGENT);
            }

            __builtin_amdgcn_s_barrier();   // all waves past MFMA reads of hl

#pragma unroll
            for (int j = 0; j < 16; ++j) {
                int idx = tid + 256 * j;
                int r = idx >> 9, c2 = idx & 511;
                u32 pk = ((u32)(vv[j] >> 16) & 0xFFFFu) | ((u32)(vv[j] >> 32) & 0xFFFF0000u);
                *(u32*)((char*)hl + (r << 11) + (((c2 >> 2) ^ (r & 7)) << 4) + ((c2 & 3) << 2)) = pk;
            }
        }

        asm volatile("s_waitcnt lgkmcnt(0)" ::: "memory");
        __builtin_amdgcn_s_barrier();
        __builtin_amdgcn_sched_barrier(0);
    }
}

// -------- Phase 2: 256x256 double-buffered 4-phase GEMM (8-phase template) --
// C = H(4096x1024) @ WhoT(32000x1024)^T + b_o. BK=64, 16 K-tiles.
// 512 thr / 8 waves (2M x 4N), per-wave 128x64 out (8x4 16x16 frags).
// LDS: A[2][256][64] + B[2][256][64] bf16 = 128 KB (granule-XOR swizzled).
// Per K-tile t: [barrier: t-1 reads done] -> issue t+1:H0-H2 (6 loads into
// freed buffer) -> vmcnt(6) (all of tile t landed, 3 half-tiles in flight) ->
// [barrier] -> 4 phases {A-quadrant ds_read; setprio(1); 16 MFMA; setprio(0)},
// t+1:H3 issued in phase 1. B-frags read once per tile. Loads never drain
// to 0 mid-loop (T3/T4); epilogue repack -> full-line NT stores.
__global__ __launch_bounds__(512, 2) void gemm_out(
    const short* __restrict__ A,
    const short* __restrict__ B,
    const float* __restrict__ bo,
    float* __restrict__ C)
{
    __shared__ __align__(16) char lds[139264];  // 128K bufs; 136K epi scratch

    // XCD-aware swizzle (grid 2000 % 8 == 0 -> bijective)
    int nwg = gridDim.x;
    int cpx = nwg >> 3;
    int bid = blockIdx.x;
    int swz = (bid & 7) * cpx + (bid >> 3);
    int bm = swz & 15;    // m fastest: consecutive blocks share the B panel
    int bn = swz >> 4;

    const int tid = threadIdx.x;
    const int lane = tid & 63;
    const int wid = tid >> 6;          // 0..7
    const int wm = wid >> 2;           // 0..1 (128-row M slice)
    const int wn = wid & 3;            // 0..3 (64-col N slice)
    const int lrow = lane & 15, kg = lane >> 4;
    const int rx = lrow & 7;

    const size_t a0 = (size_t)bm * 256;
    const size_t b0 = (size_t)bn * 256;

    const int srow8 = (lane >> 3) & 7;
    const int sxor = ((lane & 7) ^ srow8) << 3;   // element offset in 64-k row

    f32x4 acc[8][4] = {};

    // Half-tiles per K-tile: h0=A rows 0-127, h1=A rows 128-255, h2/h3 = B same.
    // One STAGEH = 16 KB = 2 issues x 512 thr x 16 B. LDS dest linear
    // (wave-uniform base + lane*16); source granule pre-XOR'd: row&7 == srow8.
#define STAGEH(TT, HH)                                                        \
    {                                                                         \
        const short* gs_ = ((HH) < 2) ? A : B;                                \
        const size_t rb_ = (((HH) < 2) ? a0 : b0) + (size_t)((HH) & 1) * 128; \
        char* db_ = lds + (((HH) < 2) ? 0 : 65536) + ((TT) & 1) * 32768       \
                    + ((HH) & 1) * 16384 + wid * 1024;                        \
        const int kk_ = (TT) * 64;                                            \
        _Pragma("unroll")                                                     \
        for (int c_ = 0; c_ < 2; ++c_) {                                      \
            const short* src_ = gs_ + (rb_ + c_ * 64 + wid * 8 + srow8) * 1024\
                                + kk_ + sxor;                                 \
            __builtin_amdgcn_global_load_lds(                                 \
                (const __attribute__((address_space(1))) void*)src_,          \
                (__attribute__((address_space(3))) void*)(db_ + c_ * 8192),   \
                16, 0, 0);                                                    \
        }                                                                     \
    }

    // prologue: stage tile 0 fully (8 loads)
    STAGEH(0, 0); STAGEH(0, 1); STAGEH(0, 2); STAGEH(0, 3);

#pragma unroll 1
    for (int t = 0; t < 16; ++t) {
        __builtin_amdgcn_sched_barrier(0);
        __builtin_amdgcn_s_barrier();        // all waves done reading tile t-1
        __builtin_amdgcn_sched_barrier(0);
        if (t + 1 < 16) {
            STAGEH(t + 1, 0); STAGEH(t + 1, 1); STAGEH(t + 1, 2);   // 6 loads
            asm volatile("s_waitcnt vmcnt(6)" ::: "memory");        // tile t in
        } else {
            asm volatile("s_waitcnt vmcnt(0)" ::: "memory");
        }
        __builtin_amdgcn_sched_barrier(0);
        __builtin_amdgcn_s_barrier();        // tile t visible to all
        __builtin_amdgcn_sched_barrier(0);

        const char* Ab = lds + (t & 1) * 32768;
        const char* Bb = lds + 65536 + (t & 1) * 32768;

        // B fragments once per tile (8 x ds_read_b128, structural-floor banks)
        bf8v bfr[4][2];
#pragma unroll
        for (int nj = 0; nj < 4; ++nj)
#pragma unroll
            for (int ks = 0; ks < 2; ++ks)
                bfr[nj][ks] = *(const bf8v*)(Bb + (wn * 64 + nj * 16 + lrow) * 128
                                             + ((((ks << 2) + kg) ^ rx) << 4));

#pragma unroll
        for (int q = 0; q < 4; ++q) {
            if (q == 1 && t + 1 < 16) STAGEH(t + 1, 3);
            bf8v af[2][2];
#pragma unroll
            for (int i = 0; i < 2; ++i)
#pragma unroll
                for (int ks = 0; ks < 2; ++ks)
                    af[i][ks] = *(const bf8v*)(Ab
                        + (wm * 128 + (q * 2 + i) * 16 + lrow) * 128
                        + ((((ks << 2) + kg) ^ rx) << 4));
            __builtin_amdgcn_sched_barrier(0);
            __builtin_amdgcn_s_setprio(1);
#pragma unroll
            for (int ks = 0; ks < 2; ++ks)
#pragma unroll
                for (int i = 0; i < 2; ++i)
#pragma unroll
                    for (int nj = 0; nj < 4; ++nj)
                        acc[q * 2 + i][nj] = __builtin_amdgcn_mfma_f32_16x16x32_bf16(
                            af[i][ks], bfr[nj][ks], acc[q * 2 + i][nj], 0, 0, 0);
            __builtin_amdgcn_s_setprio(0);
            __builtin_amdgcn_sched_barrier(0);
        }
    }
#undef STAGEH

    // ---- epilogue: repack via dead LDS (272B rows: 2-way write = free) ----
    __builtin_amdgcn_sched_barrier(0);
    __builtin_amdgcn_s_barrier();            // all LDS buffer reads complete
    char* wbase = lds + wid * 17408;         // 64 rows x 272 B per wave
#pragma unroll
    for (int half = 0; half < 2; ++half) {
#pragma unroll
        for (int nj = 0; nj < 4; ++nj) {
            float bias = bo[b0 + wn * 64 + nj * 16 + lrow];
#pragma unroll
            for (int mi2 = 0; mi2 < 4; ++mi2)
#pragma unroll
                for (int r = 0; r < 4; ++r)
                    *(float*)(wbase + (mi2 * 16 + kg * 4 + r) * 272
                              + (nj * 16 + lrow) * 4)
                        = acc[half * 4 + mi2][nj][r] + bias;
        }
        asm volatile("s_waitcnt lgkmcnt(0)" ::: "memory");
        __builtin_amdgcn_sched_barrier(0);
#pragma unroll
        for (int p = 0; p < 16; ++p) {
            int lr = p * 4 + (lane >> 4);
            f32x4 v = *(const f32x4*)(wbase + lr * 272 + (lane & 15) * 16);
            size_t row_g = a0 + wm * 128 + half * 64 + lr;
            int col_g = (int)b0 + wn * 64 + (lane & 15) * 4;
            __builtin_nontemporal_store(v, (f32x4*)&C[row_g * VOCAB + col_g]);
        }
        asm volatile("s_waitcnt lgkmcnt(0)" ::: "memory");
        __builtin_amdgcn_sched_barrier(0);
    }
}

// -------- final_state: bf16 h_127 -> f32 ------------------------------------
__global__ __launch_bounds__(256) void write_final(
    const short* __restrict__ Hlast, float* __restrict__ out) {
    int i = blockIdx.x * 256 + threadIdx.x;
    if (i < BATCH * HIDDEN) out[i] = bf2f(Hlast[i]);
}

extern "C" void kernel_launch(void* const* d_in, const int* in_sizes, int n_in,
                              void* d_out, int out_size, void* d_ws, size_t ws_size,
                              hipStream_t stream) {
    const int*   x   = (const int*)  d_in[0];
    const float* st  = (const float*)d_in[1];
    const float* Wxh = (const float*)d_in[2];
    const float* Whh = (const float*)d_in[3];
    const float* bh  = (const float*)d_in[4];
    const float* Who = (const float*)d_in[5];
    const float* bo  = (const float*)d_in[6];
    float* out = (float*)d_out;

    char* ws = (char*)d_ws;
    short* WhhT = (short*)ws;                                           // 2 MB
    short* WhoT = (short*)(ws + 2097152ull);                            // 65.536 MB
    short* H    = (short*)(ws + 2097152ull + 65536000ull);              // 8.389 MB
    short* S0   = (short*)(ws + 2097152ull + 65536000ull + 8388608ull); // 64 KB
    u32*   Htag = (u32*)  (ws + 2097152ull + 65536000ull + 8388608ull + 65536ull); // 256 KB

    transpose_f32_bf16<<<(1024/64)*(1024/64), 256, 0, stream>>>(Whh, WhhT, 1024, 1024);
    transpose_f32_bf16<<<(VOCAB/64)*(1024/64), 256, 0, stream>>>(Who, WhoT, 1024, VOCAB);
    f32_to_bf16_vec<<<(BATCH*HIDDEN + 255)/256, 256, 0, stream>>>(st, S0, BATCH*HIDDEN);
    hipMemsetAsync(Htag, 0, 2ull * BATCH * HIDDEN * sizeof(u32), stream);

    rnn_persistent<<<64, 256, 0, stream>>>(WhhT, Wxh, bh, x, S0, H, Htag);

    gemm_out<<<(4096/256) * (VOCAB/256), 512, 0, stream>>>(H, WhoT, bo, out);
    write_final<<<(BATCH*HIDDEN + 255)/256, 256, 0, stream>>>(
        H + (size_t)(SEQ - 1) * BATCH * HIDDEN, out + (size_t)SEQ * BATCH * VOCAB);
}